// Round 11
// baseline (56.365 us; speedup 1.0000x reference)
//
#include <hip/hip_runtime.h>

// ShiftMap fused, v11 = v10 per-pixel code, re-decomposed for wave parallelism:
//  - PX=1: one block per 256-px row chunk (32768 blocks). Each wave runs ONE
//    short chain (LDS read -> coords -> 4 gathers -> FMA) and retires; the
//    CU scheduler interleaves 4x more independent waves instead of 4
//    register-serialized iterations inside one wave.
//  - packed fp32 (v_pk_*) weight/coord math; pre-scaled float2 control row
//  - interior fast path w/ 4 unaligned dwordx4 row-loads
//  - XCD-aware swizzle keeps each batch's 4MB image in one XCD's L2.

static constexpr float A = -0.75f;  // PyTorch bicubic coefficient
static constexpr int NXCD = 8;

typedef float f4u __attribute__((ext_vector_type(4), aligned(4)));
typedef float f2  __attribute__((ext_vector_type(2)));

__device__ __forceinline__ void cubic_weights(float t, float* w) {
    const float tm1 = t - 1.0f;
    const float p   = t * tm1;
    w[0] = (A * p) * tm1;            // A t (t-1)^2
    w[3] = (-A * p) * t;             // A t^2 (1-t)
    const float t2 = t * t;
    w[1] = (A + 2.0f) * t2 * t - (A + 3.0f) * t2 + 1.0f;
    w[2] = 1.0f - w[0] - w[1] - w[3];  // partition of unity
}

// packed pair: t = (tx, ty) -> w[j] = (wx_j, wy_j)
__device__ __forceinline__ void cubic_weights_pk(f2 t, f2* w) {
    const f2 tm1 = t - 1.0f;
    const f2 p   = t * tm1;
    w[0] = (A * p) * tm1;
    w[3] = (-A * p) * t;
    const f2 t2 = t * t;
    w[1] = (A + 2.0f) * t2 * t - (A + 3.0f) * t2 + 1.0f;
    w[2] = 1.0f - w[0] - w[1] - w[3];
}

__global__ __launch_bounds__(256) void shiftmap_warp_kernel(
    const float* __restrict__ img,   // (B,1,H,W)
    const float* __restrict__ smap,  // (B,CH,CW,2)
    float* __restrict__ out,         // (B,1,H,W)
    int H, int W, int CH, int CW, int nblocks)
{
    // XCD-aware swizzle: dispatch d lands on XCD d%8 -> contiguous work band.
    const int d   = blockIdx.x;
    const int per = nblocks / NXCD;
    const int work = (d % NXCD) * per + d / NXCD;
    // work = ((b*H + y) * 4 + xc); 4 chunks of 256 px per row
    const int xc = work & 3;
    const int row_id = work >> 2;
    const int y = row_id & (H - 1);            // H = 1024
    const int b = row_id / H;
    const int tid = threadIdx.x;
    const int x = xc * 256 + tid;

    // padded, y-interpolated, PRE-SCALED control row, x-channel first:
    // pair c+1 = (x_shift*half_w, y_shift*half_h), c in [-1..17]
    __shared__ __align__(8) float s_row[40];

    const float scale_y = (float)((double)(CH - 1) / (double)(H - 1));
    const float scale_x = (float)((double)(CW - 1) / (double)(W - 1));
    const float half_w = 0.5f * (float)(W - 1);
    const float half_h = 0.5f * (float)(H - 1);

    if (tid < 38) {
        const int c  = (tid >> 1) - 1;                 // -1..17
        const int cc = min(max(c, 0), CW - 1);         // clamp once at stage
        const int ch = tid & 1;                        // source ch: 0=y, 1=x
        const float sy  = y * scale_y;
        const float fy0 = floorf(sy);
        const int   cy0 = (int)fy0;
        float wy[4];
        cubic_weights(sy - fy0, wy);
        float v = 0.0f;
        #pragma unroll
        for (int i = 0; i < 4; ++i) {
            const int cy = min(max(cy0 - 1 + i, 0), CH - 1);
            v += wy[i] * smap[(((size_t)b * CH + cy) * CW + cc) * 2 + ch];
        }
        const float scale = ch ? half_w : half_h;
        s_row[(c + 1) * 2 + (ch ^ 1)] = v * scale;     // swapped: x first
    }
    __syncthreads();

    const f2* __restrict__ srow2 = reinterpret_cast<const f2*>(s_row);
    const float* imgb = img + (size_t)b * H * W;
    float* outb = out + (size_t)b * H * W + (size_t)y * W;

    // ---- x-interp of control row (packed): 4 ds_read_b64 + 4 pk-FMA ----
    const float sx  = x * scale_x;
    const float fx0 = floorf(sx);
    const int   cx0 = (int)fx0;                    // 0..15
    float wx[4];
    cubic_weights(sx - fx0, wx);
    const f2 c0 = srow2[cx0],     c1 = srow2[cx0 + 1],
             c2 = srow2[cx0 + 2], c3 = srow2[cx0 + 3];
    const f2 sm = wx[0] * c0 + wx[1] * c1 + wx[2] * c2 + wx[3] * c3;

    // ---- sampling coords (packed; mesh folded analytically) ----
    f2 xy; xy.x = (float)x; xy.y = (float)y;
    const f2 pos = xy + sm;                        // (ix, iy) in pixels
    const float ixf = floorf(pos.x), iyf = floorf(pos.y);
    const int ix0 = (int)ixf, iy0 = (int)iyf;
    f2 fl; fl.x = ixf; fl.y = iyf;
    f2 w0, w1, w2, w3;
    {
        f2 ww[4];
        cubic_weights_pk(pos - fl, ww);            // .x = x-wt, .y = y-wt
        w0 = ww[0]; w1 = ww[1]; w2 = ww[2]; w3 = ww[3];
    }

    // ---- 4x4 bicubic gather ----
    float acc = 0.0f;
    if (__builtin_expect((ix0 >= 1) & (ix0 <= W - 3) &
                         (iy0 >= 1) & (iy0 <= H - 3), 1)) {
        // interior fast path: 4 unaligned float4 row-loads
        const float* p = imgb + (size_t)(iy0 - 1) * W + (ix0 - 1);
        const f4u r0 = *reinterpret_cast<const f4u*>(p);
        const f4u r1 = *reinterpret_cast<const f4u*>(p + W);
        const f4u r2 = *reinterpret_cast<const f4u*>(p + 2 * W);
        const f4u r3 = *reinterpret_cast<const f4u*>(p + 3 * W);
        acc  = w0.y * (w0.x * r0.x + w1.x * r0.y + w2.x * r0.z + w3.x * r0.w);
        acc += w1.y * (w0.x * r1.x + w1.x * r1.y + w2.x * r1.z + w3.x * r1.w);
        acc += w2.y * (w0.x * r2.x + w1.x * r2.y + w2.x * r2.z + w3.x * r2.w);
        acc += w3.y * (w0.x * r3.x + w1.x * r3.y + w2.x * r3.z + w3.x * r3.w);
    } else {
        // border: zeros padding with per-tap masks (rare)
        const float gwx[4] = {w0.x, w1.x, w2.x, w3.x};
        const float gwy[4] = {w0.y, w1.y, w2.y, w3.y};
        #pragma unroll
        for (int i = 0; i < 4; ++i) {
            const int yy = iy0 - 1 + i;
            const bool vy = (yy >= 0) && (yy < H);
            const int yc = min(max(yy, 0), H - 1);
            const float* row = imgb + (size_t)yc * W;
            float r = 0.0f;
            #pragma unroll
            for (int j = 0; j < 4; ++j) {
                const int xx = ix0 - 1 + j;
                const bool v = vy && (xx >= 0) && (xx < W);
                const int xc2 = min(max(xx, 0), W - 1);
                r += gwx[j] * (v ? row[xc2] : 0.0f);
            }
            acc += gwy[i] * r;
        }
    }
    outb[x] = acc;
}

extern "C" void kernel_launch(void* const* d_in, const int* in_sizes, int n_in,
                              void* d_out, int out_size, void* d_ws, size_t ws_size,
                              hipStream_t stream) {
    const float* img  = (const float*)d_in[0];  // (B,1,1024,1024) fp32
    const float* smap = (const float*)d_in[1];  // (B,16,16,2) fp32
    float* out = (float*)d_out;

    const int H = 1024, W = 1024;
    const int CH = 16, CW = 16;
    const int B = in_sizes[0] / (H * W);
    const int nblocks = B * H * (W / 256);   // 32768 blocks; mult of 8

    dim3 block(256);
    dim3 grid(nblocks);
    shiftmap_warp_kernel<<<grid, block, 0, stream>>>(img, smap, out,
                                                     H, W, CH, CW, nblocks);
}